// Round 22
// baseline (3686.373 us; speedup 1.0000x reference)
//
#include <hip/hip_runtime.h>
#include <hip/hip_fp16.h>

#define TT 1024
#define BB 128
#define II 256
#define HH 256
#define NG 768   // 3*H

// Static scratch: x bf16, wih^T bf16, gi f16 (bias folded in).
__device__ __align__(16) unsigned short g_xbf[(size_t)TT * BB * II];   // 67 MB
__device__ __align__(16) unsigned short g_wihB[NG * II];               // 384 KB
__device__ __align__(16) _Float16       g_gi[(size_t)TT * BB * NG];    // 201 MB

typedef __attribute__((ext_vector_type(8))) short    bfrag;
typedef __attribute__((ext_vector_type(8))) _Float16 hfrag;
typedef __attribute__((ext_vector_type(4))) float    f32x4;

__device__ __forceinline__ unsigned short f2bf(float f) {
    unsigned u = __float_as_uint(f);
    return (unsigned short)((u + 0x7fffu + ((u >> 16) & 1u)) >> 16);   // RNE
}

// ---------------- phase 1a: x f32 -> bf16 ----------------
__global__ void cvt_x_kernel(const float* __restrict__ x) {
    const int n4 = TT * BB * II / 4;
    for (int i = blockIdx.x * blockDim.x + threadIdx.x; i < n4;
         i += gridDim.x * blockDim.x) {
        float4 v = reinterpret_cast<const float4*>(x)[i];
        ushort4 o;
        o.x = f2bf(v.x); o.y = f2bf(v.y); o.z = f2bf(v.z); o.w = f2bf(v.w);
        reinterpret_cast<ushort4*>(g_xbf)[i] = o;
    }
}

// ---------------- phase 1b: wihT [k][n] -> wihB [n][k] bf16 ----------------
__global__ void cvt_wih_kernel(const float* __restrict__ wihT) {
    const int n = blockIdx.x;
    const int k = threadIdx.x;
    g_wihB[n * II + k] = f2bf(wihT[k * NG + n]);
}

// ---------------- phase 2: gi = x @ wihT + bias (MFMA bf16, f16 out) ----------------
__global__ void __launch_bounds__(256) gi_gemm_kernel(const float* __restrict__ bias) {
    __shared__ unsigned short Ab[128 * 32];
    __shared__ unsigned short Bb[128 * 32];
    const int tid = threadIdx.x;
    const int mt = blockIdx.x / 6, nt = blockIdx.x % 6;
    const int m0 = mt * 128, n0 = nt * 128;
    const int l = tid & 63, w = tid >> 6;
    const int wr = w >> 1, wc = w & 1;
    const int srow = tid >> 2, scol = (tid & 3) * 8;

    f32x4 acc[4][4] = {};

    for (int ks = 0; ks < 8; ++ks) {
        const int k0 = ks * 32;
        __syncthreads();
        #pragma unroll
        for (int c = 0; c < 2; ++c) {
            const int row = c * 64 + srow;
            *reinterpret_cast<uint4*>(&Ab[row * 32 + scol]) =
                *reinterpret_cast<const uint4*>(&g_xbf[(size_t)(m0 + row) * II + k0 + scol]);
            *reinterpret_cast<uint4*>(&Bb[row * 32 + scol]) =
                *reinterpret_cast<const uint4*>(&g_wihB[(n0 + row) * II + k0 + scol]);
        }
        __syncthreads();
        bfrag af[4], bf[4];
        #pragma unroll
        for (int i = 0; i < 4; ++i) {
            af[i] = *reinterpret_cast<const bfrag*>(
                        &Ab[(wr * 64 + i * 16 + (l & 15)) * 32 + (l >> 4) * 8]);
            bf[i] = *reinterpret_cast<const bfrag*>(
                        &Bb[(wc * 64 + i * 16 + (l & 15)) * 32 + (l >> 4) * 8]);
        }
        #pragma unroll
        for (int mi = 0; mi < 4; ++mi)
            #pragma unroll
            for (int ni = 0; ni < 4; ++ni)
                acc[mi][ni] = __builtin_amdgcn_mfma_f32_16x16x32_bf16(
                                  af[mi], bf[ni], acc[mi][ni], 0, 0, 0);
    }
    #pragma unroll
    for (int mi = 0; mi < 4; ++mi) {
        const int grow = m0 + wr * 64 + mi * 16 + (l >> 4) * 4;
        #pragma unroll
        for (int ni = 0; ni < 4; ++ni) {
            const int gcol = n0 + wc * 64 + ni * 16 + (l & 15);
            const float bv = bias[gcol];
            #pragma unroll
            for (int q = 0; q < 4; ++q)
                g_gi[(size_t)(grow + q) * NG + gcol] = (_Float16)(acc[mi][ni][q] + bv);
        }
    }
}

// ---------------- phase 3: recurrence, pipelined AGPR->VGPR copies ----------------
// r17 (passing, 1219 us rec) measured VALU 1340 + MFMA 1590 cyc/step with
// the pipes SERIALIZED: the compiler emits each frag's v_accvgpr_read
// immediately before its consuming MFMA, and the VALU-write -> MFMA-srcB
// hazard forces multi-cycle wait padding on every one of the 48 copies.
// Fix (all consumed paths stay compiler-visible): software-pipeline the
// copies ONE K-TILE AHEAD. Explicit v_accvgpr_read copy-asms (read AGPRs
// written once at init -> no write hazard; write VGPR temps consumed >= 6
// MFMAs (~100 cyc) later -> hazard satisfied by distance), double-buffered
// 2 x 6 frags = 48 VGPRs; MFMA is the BUILTIN reading the VGPR temps
// (numerics byte-identical to r17). Arch ~= 48 tmp + 24 acc + ~45 misc =
// ~117 <= 128; AGPR = 192 pinned frags. Geometry = r17.
#define MFB(ACC, AV, BV)                                                    \
    ACC = __builtin_amdgcn_mfma_f32_16x16x32_f16((AV), (BV), (ACC), 0, 0, 0)

#define CP(D, S) asm volatile("v_accvgpr_read_b32 %0, %1" : "=v"(D) : "a"(S))

// copy one pinned frag (4 dwords) into a VGPR temp
#define CPF(TMP, FRAG)                                                      \
    {                                                                       \
        const uint4 _u = __builtin_bit_cast(uint4, FRAG);                   \
        unsigned _a, _b, _c, _d;                                            \
        CP(_a, _u.x); CP(_b, _u.y); CP(_c, _u.z); CP(_d, _u.w);             \
        TMP = __builtin_bit_cast(hfrag, make_uint4(_a, _b, _c, _d));        \
    }

#define LDB1(NAME, CB, KT)                                                  \
    hfrag NAME;                                                             \
    _Pragma("unroll")                                                       \
    for (int e = 0; e < 8; ++e)                                             \
        NAME[e] = (_Float16)whhT[(size_t)((KT) * 32 + g8 + e) * NG + (CB) + c]; \
    asm("" : "+a"(NAME));

#define DECL8(P, CB)                                                        \
    LDB1(P##_0, CB, 0) LDB1(P##_1, CB, 1) LDB1(P##_2, CB, 2)                \
    LDB1(P##_3, CB, 3) LDB1(P##_4, CB, 4) LDB1(P##_5, CB, 5)                \
    LDB1(P##_6, CB, 6) LDB1(P##_7, CB, 7)

// copy all 6 frags of k-tile KT into temp buffer S
#define KCOPY(S, KT)                                                        \
    CPF(tR0##S, BR0_##KT) CPF(tR1##S, BR1_##KT)                             \
    CPF(tZ0##S, BZ0_##KT) CPF(tZ1##S, BZ1_##KT)                             \
    CPF(tN0##S, BN0_##KT) CPF(tN1##S, BN1_##KT)

// run the 6 MFMAs of k-tile KT from temp buffer S
#define KMFMA(S, KT)                                                        \
    {                                                                       \
        const hfrag A = *reinterpret_cast<const hfrag*>(hl + (KT) * 32 + g8); \
        MFB(R0, A, tR0##S); MFB(Z0, A, tZ0##S);                             \
        MFB(R1, A, tR1##S); MFB(Z1, A, tZ1##S);                             \
        MFB(N0, A, tN0##S); MFB(N1, A, tN1##S);                             \
    }

__global__ void __launch_bounds__(512, 1) gru_rec_kernel(
    const float* __restrict__ h0, const float* __restrict__ whhT,
    float* __restrict__ out)
{
    __shared__ __align__(16) _Float16 hbuf[2][HH];   // 1 KB ping-pong h (f16)

    const int t   = threadIdx.x;
    const int b   = blockIdx.x;
    const int w   = t >> 6;             // wave 0..7
    const int l   = t & 63;
    const int c   = l & 15;             // col within tile
    const int sel = l >> 4;             // 0..3; sel&1 picks tile half
    const int g8  = sel * 8;            // k-sub-chunk base
    const int cw  = w * 16;
    const int j   = (sel & 1) * 128 + cw + c;   // this lane's output column

    // --- 48 whh B-fragments, pinned to AGPR once ---
    DECL8(BR0, cw)        DECL8(BR1, 128 + cw)
    DECL8(BZ0, 256 + cw)  DECL8(BZ1, 384 + cw)
    DECL8(BN0, 512 + cw)  DECL8(BN1, 640 + cw)

    // --- init h ---
    float hp = h0[b * HH + j];
    hbuf[0][j] = (_Float16)hp;          // duplicate writes: same value
    __syncthreads();

    for (int ts = 0; ts < TT; ++ts) {
        const _Float16* hl  = hbuf[ts & 1];
        _Float16*       hn_ = hbuf[(ts & 1) ^ 1];

        // gi for this step (bias pre-folded; hides under the MFMA block)
        const _Float16* gb = g_gi + ((size_t)ts * BB + b) * NG + j;
        const float gR = (float)gb[0];
        const float gZ = (float)gb[256];
        const float gN = (float)gb[512];

        f32x4 R0 = {0.f,0.f,0.f,0.f}, R1 = {0.f,0.f,0.f,0.f};
        f32x4 Z0 = {0.f,0.f,0.f,0.f}, Z1 = {0.f,0.f,0.f,0.f};
        f32x4 N0 = {0.f,0.f,0.f,0.f}, N1 = {0.f,0.f,0.f,0.f};

        hfrag tR0a, tR1a, tZ0a, tZ1a, tN0a, tN1a;   // temp buffer a
        hfrag tR0b, tR1b, tZ0b, tZ1b, tN0b, tN1b;   // temp buffer b

        // software pipeline: copy k-tile KT+1 while MFMA-ing k-tile KT
        KCOPY(a, 0)
        KCOPY(b, 1) KMFMA(a, 0)
        KCOPY(a, 2) KMFMA(b, 1)
        KCOPY(b, 3) KMFMA(a, 2)
        KCOPY(a, 4) KMFMA(b, 3)
        KCOPY(b, 5) KMFMA(a, 4)
        KCOPY(a, 6) KMFMA(b, 5)
        KCOPY(b, 7) KMFMA(a, 6)
        KMFMA(b, 7)

        // all C rows equal (duplicated A rows): reg 0 = this col's gh
        const float sR = (sel & 1) ? R1[0] : R0[0];
        const float sZ = (sel & 1) ? Z1[0] : Z0[0];
        const float sN = (sel & 1) ? N1[0] : N0[0];

        const float r  = 1.f / (1.f + __expf(-(sR + gR)));
        const float z  = 1.f / (1.f + __expf(-(sZ + gZ)));
        const float e  = __expf(2.f * (gN + r * sN));   // tanh
        const float n  = 1.f - 2.f / (e + 1.f);
        const float hv = (1.f - z) * n + z * hp;

        hp = hv;
        hn_[j] = (_Float16)hv;          // duplicate writes: same value
        if (ts == TT - 1) out[b * HH + j] = hv;
        __syncthreads();
    }
}

extern "C" void kernel_launch(void* const* d_in, const int* in_sizes, int n_in,
                              void* d_out, int out_size, void* d_ws, size_t ws_size,
                              hipStream_t stream) {
    const float* x    = (const float*)d_in[0];
    const float* h0   = (const float*)d_in[1];
    const float* wihT = (const float*)d_in[2];
    const float* whhT = (const float*)d_in[3];
    const float* bias = (const float*)d_in[4];
    float*       out  = (float*)d_out;

    cvt_x_kernel<<<2048, 256, 0, stream>>>(x);
    cvt_wih_kernel<<<NG, 256, 0, stream>>>(wihT);
    gi_gemm_kernel<<<1024 * 6, 256, 0, stream>>>(bias);
    gru_rec_kernel<<<BB, 512, 0, stream>>>(h0, whhT, out);
}